// Round 8
// baseline (412.392 us; speedup 1.0000x reference)
//
#include <hip/hip_runtime.h>
#include <hip/hip_bf16.h>
#include <stdint.h>

#define NNODES 100000
#define DF 64
#define NEDGES 1600000
#define ND (NNODES * DF)     // 6,400,000
#define BKT 100              // targets per bucket
#define NBUCK 1000           // BKT*NBUCK == NNODES
#define CHUNK 128            // edges per wave in agg_k
#define NCHUNK (NEDGES / CHUNK)   // 12500
#define NSL 4                // dim slices for agg locality
#define SW 16                // dims per slice (NSL*SW == DF)
#define SLN ((size_t)NNODES * SW) // elements per slice

// ---------- helpers ----------
static __device__ __forceinline__ float bf2f(unsigned short u) {
    union { uint32_t i; float f; } c; c.i = ((uint32_t)u) << 16; return c.f;
}
static __device__ __forceinline__ unsigned short f2bf(float f) {
    union { __hip_bfloat16 b; unsigned short u; } c; c.b = __float2bfloat16(f); return c.u;
}
static __device__ __forceinline__ void unpack2(uint32_t u, float& lo, float& hi) {
    union { uint32_t i; float f; } a, b;
    a.i = u << 16; b.i = u & 0xFFFF0000u;
    lo = a.f; hi = b.f;
}

// ---------- dtype detector: flags[0]=bf16?, flags[1]=int64? ----------
__global__ void detect_k(const unsigned short* __restrict__ x,
                         const unsigned int* __restrict__ ei,
                         int* __restrict__ flags) {
    __shared__ int cnt_sane, cnt_odd_nz;
    if (threadIdx.x == 0) { cnt_sane = 0; cnt_odd_nz = 0; }
    __syncthreads();
    unsigned short s = x[threadIdx.x * 2];
    unsigned short m = s & 0x7FFF;
    if (m < 0x0080 || (m >= 0x3000 && m <= 0x4200)) atomicAdd(&cnt_sane, 1);
    if (threadIdx.x < 64) {
        if (ei[threadIdx.x * 2 + 1] != 0u) atomicAdd(&cnt_odd_nz, 1);
    }
    __syncthreads();
    if (threadIdx.x == 0) {
        flags[0] = (cnt_sane >= 192) ? 1 : 0;
        flags[1] = (cnt_odd_nz == 0) ? 1 : 0;
    }
}

// ---------- weight canonicalization -> fp32 TRANSPOSED ----------
// WfMT layout: [half][k][j] : half 0 = Wm_s, half 1 = Wm_t ; element = W[j][k]
// WfUT layout: half 0 = Wu_x, half 1 = Wu_m
// prm: [0:64)=b_msg [64:128)=b_upd [128:192)=gamma [192:256)=beta [256:320)=0
__global__ void wconv_k(const int* __restrict__ flags,
                        const void* __restrict__ Wm, const void* __restrict__ Wu,
                        const void* __restrict__ bm, const void* __restrict__ bu,
                        const void* __restrict__ ga, const void* __restrict__ be,
                        float* __restrict__ WfMT, float* __restrict__ WfUT,
                        float* __restrict__ prm) {
    const int bf = flags[0];
    int i = blockIdx.x * 256 + threadIdx.x;
    if (i < 16384) {
        const void* src = (i < 8192) ? Wm : Wu;
        float* dst = (i < 8192) ? WfMT : WfUT;
        int ii = i & 8191, j = ii >> 6, k = ii & 63;
        int si = (j & 63) * 128 + ((j >> 6) ? 64 : 0) + k;
        float v = bf ? bf2f(((const unsigned short*)src)[si]) : ((const float*)src)[si];
        dst[(j >> 6) * 4096 + k * 64 + (j & 63)] = v;
    } else if (i < 16384 + 320) {
        int t = i - 16384, which = t >> 6, k = t & 63;
        if (which == 4) { prm[t] = 0.f; }
        else {
            const void* p = (which == 0) ? bm : (which == 1) ? bu : (which == 2) ? ga : be;
            prm[t] = bf ? bf2f(((const unsigned short*)p)[k]) : ((const float*)p)[k];
        }
    }
}

// ---------- generic row-matmul: out[n][j] = sum_k in[n][k] * WT[k][j] + bias[j] ----------
// wave = node (grid-stride), lane = output dim j. Weights in 64 registers per lane.
// of=1 -> fp32 row-major output; of=0 -> bf16 SLICED output [NSL][N][SW].
__global__ __launch_bounds__(256, 1) void mm_k(const int* __restrict__ flags,
                                               const void* __restrict__ xv,
                                               const float* __restrict__ WT,
                                               const float* __restrict__ bias,
                                               void* __restrict__ outv,
                                               int of) {
    const int lane = threadIdx.x & 63;
    const int wib = __builtin_amdgcn_readfirstlane(threadIdx.x >> 6);
    const int bf = flags[0];

    float w[64];
    #pragma unroll
    for (int k = 0; k < 64; ++k) w[k] = WT[k * 64 + lane];
    const float bs = bias[lane];

    const int wv = blockIdx.x * 4 + wib;
    const int nw = gridDim.x * 4;
    for (int n = wv; n < NNODES; n += nw) {
        float a0 = 0.f, a1 = 0.f, a2 = 0.f, a3 = 0.f;
        if (bf) {
            const uint4* xr = (const uint4*)((const unsigned short*)xv + (size_t)n * DF);
            #pragma unroll
            for (int q = 0; q < 8; ++q) {
                uint4 v = xr[q];
                float x0,x1,x2,x3,x4,x5,x6,x7;
                unpack2(v.x, x0, x1); unpack2(v.y, x2, x3);
                unpack2(v.z, x4, x5); unpack2(v.w, x6, x7);
                a0 = fmaf(x0, w[8*q+0], a0); a1 = fmaf(x1, w[8*q+1], a1);
                a2 = fmaf(x2, w[8*q+2], a2); a3 = fmaf(x3, w[8*q+3], a3);
                a0 = fmaf(x4, w[8*q+4], a0); a1 = fmaf(x5, w[8*q+5], a1);
                a2 = fmaf(x6, w[8*q+6], a2); a3 = fmaf(x7, w[8*q+7], a3);
            }
        } else {
            const float4* xr = (const float4*)((const float*)xv + (size_t)n * DF);
            #pragma unroll
            for (int q = 0; q < 16; ++q) {
                float4 v = xr[q];
                a0 = fmaf(v.x, w[4*q+0], a0); a1 = fmaf(v.y, w[4*q+1], a1);
                a2 = fmaf(v.z, w[4*q+2], a2); a3 = fmaf(v.w, w[4*q+3], a3);
            }
        }
        float r = (a0 + a1) + (a2 + a3) + bs;
        if (of) {
            ((float*)outv)[(size_t)n * DF + lane] = r;
        } else {
            size_t gi = (size_t)(lane >> 4) * SLN + (size_t)n * SW + (lane & 15);
            ((unsigned short*)outv)[gi] = f2bf(r);
        }
    }
}

// ---------- bucket histogram (LDS pre-aggregated) ----------
__global__ __launch_bounds__(256) void bhist_k(const int* __restrict__ flags,
                                               const int* __restrict__ ei,
                                               int* __restrict__ BktCnt) {
    __shared__ int h[NBUCK];
    const int i64 = flags[1];
    for (int i = threadIdx.x; i < NBUCK; i += 256) h[i] = 0;
    __syncthreads();
    int stride = gridDim.x * 256;
    for (int e = blockIdx.x * 256 + threadIdx.x; e < NEDGES; e += stride) {
        int tgt = i64 ? ei[4*e + 2] : ei[2*e + 1];
        if ((unsigned)tgt < NNODES) atomicAdd(&h[tgt / BKT], 1);
    }
    __syncthreads();
    for (int b = threadIdx.x; b < NBUCK; b += 256)
        if (h[b]) atomicAdd(BktCnt + b, h[b]);
}

// ---------- scan of 1000 bucket counts ----------
__global__ __launch_bounds__(1024) void bscan_k(const int* __restrict__ BktCnt,
                                                int* __restrict__ BktOff,
                                                int* __restrict__ BktCur) {
    __shared__ int lds[1024];
    int t = threadIdx.x;
    int c = (t < NBUCK) ? BktCnt[t] : 0;
    lds[t] = c;
    __syncthreads();
    for (int off = 1; off < 1024; off <<= 1) {
        int add = (t >= off) ? lds[t - off] : 0;
        __syncthreads();
        lds[t] += add;
        __syncthreads();
    }
    if (t < NBUCK) {
        int ex = lds[t] - c;
        BktOff[t] = ex;
        BktCur[t] = ex;
    }
    if (t == NBUCK - 1) BktOff[NBUCK] = lds[t];
}

// ---------- bucket fill: two-pass binning, packed (tl<<24 | src) ----------
__global__ __launch_bounds__(256) void bfill_k(const int* __restrict__ flags,
                                               const int* __restrict__ ei,
                                               int* __restrict__ BktCur,
                                               int* __restrict__ BktE) {
    __shared__ int h[NBUCK], h2[NBUCK], basee[NBUCK];
    const int i64 = flags[1];
    for (int i = threadIdx.x; i < NBUCK; i += 256) { h[i] = 0; h2[i] = 0; }
    __syncthreads();
    const int stride = gridDim.x * 256;
    for (int e = blockIdx.x * 256 + threadIdx.x; e < NEDGES; e += stride) {
        int tgt = i64 ? ei[4*e + 2] : ei[2*e + 1];
        if ((unsigned)tgt < NNODES) atomicAdd(&h[tgt / BKT], 1);
    }
    __syncthreads();
    for (int b = threadIdx.x; b < NBUCK; b += 256)
        if (h[b]) basee[b] = atomicAdd(BktCur + b, h[b]);
    __syncthreads();
    for (int e = blockIdx.x * 256 + threadIdx.x; e < NEDGES; e += stride) {
        int src, tgt;
        if (i64) { src = ei[4*e]; tgt = ei[4*e + 2]; }
        else     { src = ei[2*e]; tgt = ei[2*e + 1]; }
        if ((unsigned)tgt >= NNODES) continue;
        int b = tgt / BKT;
        int tl = tgt - b * BKT;
        int r = atomicAdd(&h2[b], 1);
        BktE[basee[b] + r] = (tl << 24) | (src & 0xFFFFFF);
    }
}

// ---------- per-bucket counting sort by target -> CsrSrc + Row ----------
__global__ __launch_bounds__(256) void tsort_k(const int* __restrict__ BktOff,
                                               const int* __restrict__ BktE,
                                               int* __restrict__ CsrSrc,
                                               int* __restrict__ Row) {
    __shared__ int oc[128], excl[128], cur[128];
    const int tid = threadIdx.x;
    const int b = blockIdx.x;
    const int s = BktOff[b], e = BktOff[b + 1];
    const int n = e - s;
    if (tid < 128) { oc[tid] = 0; }
    __syncthreads();
    for (int i = tid; i < n; i += 256)
        atomicAdd(&oc[((unsigned)BktE[s + i]) >> 24], 1);
    __syncthreads();
    if (tid < 128) excl[tid] = (tid > 0) ? oc[tid - 1] : 0;
    __syncthreads();
    for (int off = 1; off < 128; off <<= 1) {
        int add = (tid >= off && tid < 128) ? excl[tid - off] : 0;
        __syncthreads();
        if (tid < 128) excl[tid] += add;
        __syncthreads();
    }
    if (tid < BKT) {
        Row[b * BKT + tid] = s + excl[tid];
        cur[tid] = excl[tid];
    }
    if (b == 0 && tid == 0) Row[NNODES] = NEDGES;
    __syncthreads();
    for (int i = tid; i < n; i += 256) {
        int v = BktE[s + i];
        int tl = ((unsigned)v) >> 24;
        int p = atomicAdd(&cur[tl], 1);
        CsrSrc[s + p] = v & 0xFFFFFF;
    }
}

// ---------- aggregation: dim-sliced for XCD-L2 residency ----------
// Ps/Pt/Msg are sliced [NSL][N][SW]. Block g: slice = g&3 (round-robin XCD =>
// slice s lives on XCDs {s, s+4}; 3.2 MB slice fits the 4 MB XCD L2 -> gathers
// become L2 hits). Wave handles chunk cb*4+wib; lanes = 4 edge-slots x 16 dims.
__global__ __launch_bounds__(256) void agg_k(const unsigned short* __restrict__ Ps,
                                             const unsigned short* __restrict__ Pt,
                                             const int* __restrict__ Row,
                                             const int* __restrict__ CsrSrc,
                                             unsigned short* __restrict__ Msg) {
    const int lane = threadIdx.x & 63;
    const int wib = __builtin_amdgcn_readfirstlane(threadIdx.x >> 6);
    const int sl = blockIdx.x & 3;
    const int cb = blockIdx.x >> 2;
    const int c = cb * 4 + wib;
    if (c >= NCHUNK) return;
    const int d  = lane & 15;
    const int eg = lane >> 4;     // edge slot 0..3

    const unsigned short* Ps_s = Ps + (size_t)sl * SLN;
    const unsigned short* Pt_s = Pt + (size_t)sl * SLN;
    unsigned short*       Ms_s = Msg + (size_t)sl * SLN;

    const int eA = c * CHUNK;
    const int hiB = (c == NCHUNK - 1) ? (NEDGES + 1) : (eA + CHUNK);

    // t_lo = first t with Row[t] >= eA ; t_hi = first t with Row[t] >= hiB
    int lo = 0, hi = NNODES + 1;
    while (lo < hi) { int mid = (lo + hi) >> 1; if (Row[mid] >= eA) hi = mid; else lo = mid + 1; }
    const int t_lo = lo;
    lo = t_lo; hi = NNODES + 1;
    while (lo < hi) { int mid = (lo + hi) >> 1; if (Row[mid] >= hiB) hi = mid; else lo = mid + 1; }
    int t_hi = lo;
    if (t_hi > NNODES) t_hi = NNODES;

    for (int t = t_lo; t < t_hi; ++t) {
        const int segS = Row[t], segE = Row[t + 1];
        const int deg = segE - segS;
        float ptv = bf2f(Pt_s[(size_t)t * SW + d]);
        float macc = 0.f;
        for (int i = segS; i < segE; i += 8) {
            int idxA = i + eg;
            int idxB = idxA + 4;
            int iA = (idxA < segE) ? idxA : segS;
            int iB = (idxB < segE) ? idxB : segS;
            int sA = CsrSrc[iA]; if ((unsigned)sA >= NNODES) sA = 0;
            int sB = CsrSrc[iB]; if ((unsigned)sB >= NNODES) sB = 0;
            float pA = bf2f(Ps_s[(size_t)sA * SW + d]);
            float pB = bf2f(Ps_s[(size_t)sB * SW + d]);
            float vA = (idxA < segE) ? fmaxf(pA + ptv, 0.f) : 0.f;
            float vB = (idxB < segE) ? fmaxf(pB + ptv, 0.f) : 0.f;
            macc += vA + vB;
        }
        // reduce across the 4 edge-slot groups (lanes differing in bits 4,5)
        macc += __shfl_xor(macc, 16, 64);
        macc += __shfl_xor(macc, 32, 64);
        float mval = (deg > 0) ? (macc / (float)deg) : 0.f;
        if (lane < 16) Ms_s[(size_t)t * SW + d] = f2bf(mval);
    }
}

// ---------- u2: r = relu(t1 + Msg@Wu_m^T) + x ; LayerNorm ; out ----------
// wave = node, lane = dim. Only Wu_m (64 floats) in registers. Msg is sliced.
__global__ __launch_bounds__(256, 1) void u2_k(const int* __restrict__ flags,
                                               const void* __restrict__ xv,
                                               const unsigned short* __restrict__ Msg,
                                               const float* __restrict__ t1,
                                               const float* __restrict__ WT,
                                               const float* __restrict__ prm,
                                               void* __restrict__ outv) {
    const int lane = threadIdx.x & 63;
    const int wib = __builtin_amdgcn_readfirstlane(threadIdx.x >> 6);
    const int bf = flags[0];

    float w[64];
    #pragma unroll
    for (int k = 0; k < 64; ++k) w[k] = WT[k * 64 + lane];
    const float ga = prm[128 + lane];
    const float be = prm[192 + lane];

    const unsigned short* x16 = (const unsigned short*)xv;
    const float* xf = (const float*)xv;

    const int wv = blockIdx.x * 4 + wib;
    const int nw = gridDim.x * 4;
    for (int n = wv; n < NNODES; n += nw) {
        float b0 = 0.f, b1 = 0.f, b2 = 0.f, b3 = 0.f;
        #pragma unroll
        for (int s4 = 0; s4 < NSL; ++s4) {
            const uint4* mw = (const uint4*)(Msg + (size_t)s4 * SLN + (size_t)n * SW);
            #pragma unroll
            for (int q = 0; q < 2; ++q) {
                uint4 v = mw[q];
                const int kb = s4 * 16 + q * 8;
                float m0,m1,m2,m3,m4,m5,m6,m7;
                unpack2(v.x, m0, m1); unpack2(v.y, m2, m3);
                unpack2(v.z, m4, m5); unpack2(v.w, m6, m7);
                b0 = fmaf(m0, w[kb+0], b0); b1 = fmaf(m1, w[kb+1], b1);
                b2 = fmaf(m2, w[kb+2], b2); b3 = fmaf(m3, w[kb+3], b3);
                b0 = fmaf(m4, w[kb+4], b0); b1 = fmaf(m5, w[kb+5], b1);
                b2 = fmaf(m6, w[kb+6], b2); b3 = fmaf(m7, w[kb+7], b3);
            }
        }
        size_t gi = (size_t)n * DF + lane;
        float t  = t1[gi];
        float xl = bf ? bf2f(x16[gi]) : xf[gi];
        float u = fmaxf((b0 + b1) + (b2 + b3) + t, 0.f);
        float r = u + xl;

        float s = r, s2 = r * r;
        #pragma unroll
        for (int m = 1; m < 64; m <<= 1) {
            s  += __shfl_xor(s, m, 64);
            s2 += __shfl_xor(s2, m, 64);
        }
        float mu  = s * (1.0f / 64.0f);
        float var = fmaxf(s2 * (1.0f / 64.0f) - mu * mu, 0.f);
        float o = (r - mu) * rsqrtf(var + 1e-5f) * ga + be;

        if (bf) ((__hip_bfloat16*)outv)[gi] = __float2bfloat16(o);
        else    ((float*)outv)[gi] = o;
    }
}

extern "C" void kernel_launch(void* const* d_in, const int* in_sizes, int n_in,
                              void* d_out, int out_size, void* d_ws, size_t ws_size,
                              hipStream_t stream) {
    const void* x  = d_in[0];
    const int*  ei = (const int*)d_in[1];
    const void* Wm = d_in[2];
    const void* bm = d_in[3];
    const void* Wu = d_in[4];
    const void* bu = d_in[5];
    const void* ga = d_in[6];
    const void* be = d_in[7];

    char* ws = (char*)d_ws;
    size_t off = 0;
    unsigned short* Ps  = (unsigned short*)(ws + off); off += (size_t)ND * 2;   // 12.8 MB (sliced)
    unsigned short* Pt  = (unsigned short*)(ws + off); off += (size_t)ND * 2;   // 12.8 MB (sliced)
    unsigned short* Msg = (unsigned short*)(ws + off); off += (size_t)ND * 2;   // 12.8 MB (sliced)
    int*   BktE   = (int*)(ws + off); off += (size_t)NEDGES * 4;                // 6.4 MB
    int*   CsrSrc = (int*)(ws + off); off += (size_t)NEDGES * 4;                // 6.4 MB
    int*   Row    = (int*)(ws + off); off += (size_t)(NNODES + 1) * 4;
    int*   BktCnt = (int*)(ws + off); off += NBUCK * 4;                         // memset 0
    int*   BktOff = (int*)(ws + off); off += (NBUCK + 1) * 4;
    int*   BktCur = (int*)(ws + off); off += NBUCK * 4;
    int*   flg    = (int*)(ws + off); off += 16;
    float* WfMT   = (float*)(ws + off); off += 8192 * 4;
    float* WfUT   = (float*)(ws + off); off += 8192 * 4;
    float* prm    = (float*)(ws + off); off += 320 * 4;

    // t1 (fp32, 25.6 MB) reuses Ps+Pt region — valid because mm_k(t1) runs AFTER agg_k.
    float* t1 = (float*)Ps;

    (void)hipMemsetAsync(BktCnt, 0, NBUCK * 4, stream);

    detect_k<<<1, 256, 0, stream>>>((const unsigned short*)x, (const unsigned int*)ei, flg);
    // 66 blocks: covers 16384 weight elems + 320 prm elems (65 blocks left
    // prm[256..320) — the zero-bias slot — uninitialized; latent bug fixed)
    wconv_k<<<66, 256, 0, stream>>>(flg, Wm, Wu, bm, bu, ga, be, WfMT, WfUT, prm);

    // Ps = x@Wm_s^T (no bias -> zero slot prm+256) ; Pt = x@Wm_t^T + b_msg  (sliced bf16)
    mm_k<<<1024, 256, 0, stream>>>(flg, x, WfMT,        prm + 256, Ps, 0);
    mm_k<<<1024, 256, 0, stream>>>(flg, x, WfMT + 4096, prm,       Pt, 0);

    bhist_k<<<256, 256, 0, stream>>>(flg, ei, BktCnt);
    bscan_k<<<1, 1024, 0, stream>>>(BktCnt, BktOff, BktCur);
    bfill_k<<<128, 256, 0, stream>>>(flg, ei, BktCur, BktE);
    tsort_k<<<NBUCK, 256, 0, stream>>>(BktOff, BktE, CsrSrc, Row);

    // 12500 blocks: slice = bid&3 (XCD-paired), 4 chunks per block (one per wave)
    agg_k<<<NCHUNK, 256, 0, stream>>>(Ps, Pt, Row, CsrSrc, Msg);

    // t1 = x@Wu_x^T + b_upd (fp32 row-major), overwrites Ps/Pt (now dead)
    mm_k<<<1024, 256, 0, stream>>>(flg, x, WfUT, prm + 64, t1, 1);

    u2_k<<<1024, 256, 0, stream>>>(flg, x, Msg, t1, WfUT + 4096, prm, d_out);
}

// Round 9
// 404.646 us; speedup vs baseline: 1.0191x; 1.0191x over previous
//
#include <hip/hip_runtime.h>
#include <hip/hip_bf16.h>
#include <stdint.h>

#define NNODES 100000
#define DF 64
#define NEDGES 1600000
#define ND (NNODES * DF)     // 6,400,000
#define BKT 100              // targets per bucket
#define NBUCK 1000           // BKT*NBUCK == NNODES
#define CHUNK 128            // edges per wave in agg_k
#define NCHUNK (NEDGES / CHUNK)   // 12500
#define NSL 4                // dim slices for agg locality
#define SW 16                // dims per slice (NSL*SW == DF)
#define SLN ((size_t)NNODES * SW) // elements per slice

// ---------- helpers ----------
static __device__ __forceinline__ float bf2f(unsigned short u) {
    union { uint32_t i; float f; } c; c.i = ((uint32_t)u) << 16; return c.f;
}
static __device__ __forceinline__ unsigned short f2bf(float f) {
    union { __hip_bfloat16 b; unsigned short u; } c; c.b = __float2bfloat16(f); return c.u;
}
static __device__ __forceinline__ void unpack2(uint32_t u, float& lo, float& hi) {
    union { uint32_t i; float f; } a, b;
    a.i = u << 16; b.i = u & 0xFFFF0000u;
    lo = a.f; hi = b.f;
}

// ---------- dtype detector: flags[0]=bf16?, flags[1]=int64? ----------
__global__ void detect_k(const unsigned short* __restrict__ x,
                         const unsigned int* __restrict__ ei,
                         int* __restrict__ flags) {
    __shared__ int cnt_sane, cnt_odd_nz;
    if (threadIdx.x == 0) { cnt_sane = 0; cnt_odd_nz = 0; }
    __syncthreads();
    unsigned short s = x[threadIdx.x * 2];
    unsigned short m = s & 0x7FFF;
    if (m < 0x0080 || (m >= 0x3000 && m <= 0x4200)) atomicAdd(&cnt_sane, 1);
    if (threadIdx.x < 64) {
        if (ei[threadIdx.x * 2 + 1] != 0u) atomicAdd(&cnt_odd_nz, 1);
    }
    __syncthreads();
    if (threadIdx.x == 0) {
        flags[0] = (cnt_sane >= 192) ? 1 : 0;
        flags[1] = (cnt_odd_nz == 0) ? 1 : 0;
    }
}

// ---------- weight canonicalization -> fp32 TRANSPOSED ----------
// WfMT layout: [half][k][j] : half 0 = Wm_s, half 1 = Wm_t ; element = W[j][k]
// WfUT layout: half 0 = Wu_x, half 1 = Wu_m
// prm: [0:64)=b_msg [64:128)=b_upd [128:192)=gamma [192:256)=beta [256:320)=0
__global__ void wconv_k(const int* __restrict__ flags,
                        const void* __restrict__ Wm, const void* __restrict__ Wu,
                        const void* __restrict__ bm, const void* __restrict__ bu,
                        const void* __restrict__ ga, const void* __restrict__ be,
                        float* __restrict__ WfMT, float* __restrict__ WfUT,
                        float* __restrict__ prm) {
    const int bf = flags[0];
    int i = blockIdx.x * 256 + threadIdx.x;
    if (i < 16384) {
        const void* src = (i < 8192) ? Wm : Wu;
        float* dst = (i < 8192) ? WfMT : WfUT;
        int ii = i & 8191, j = ii >> 6, k = ii & 63;
        int si = (j & 63) * 128 + ((j >> 6) ? 64 : 0) + k;
        float v = bf ? bf2f(((const unsigned short*)src)[si]) : ((const float*)src)[si];
        dst[(j >> 6) * 4096 + k * 64 + (j & 63)] = v;
    } else if (i < 16384 + 320) {
        int t = i - 16384, which = t >> 6, k = t & 63;
        if (which == 4) { prm[t] = 0.f; }
        else {
            const void* p = (which == 0) ? bm : (which == 1) ? bu : (which == 2) ? ga : be;
            prm[t] = bf ? bf2f(((const unsigned short*)p)[k]) : ((const float*)p)[k];
        }
    }
}

// ---------- generic row-matmul: out[n][j] = sum_k in[n][k] * WT[k][j] + bias[j] ----------
// wave = node (grid-stride), lane = output dim j. Weights in 64 registers per lane.
// of=1 -> fp32 row-major output; of=0 -> bf16 SLICED output [NSL][N][SW].
__global__ __launch_bounds__(256, 1) void mm_k(const int* __restrict__ flags,
                                               const void* __restrict__ xv,
                                               const float* __restrict__ WT,
                                               const float* __restrict__ bias,
                                               void* __restrict__ outv,
                                               int of) {
    const int lane = threadIdx.x & 63;
    const int wib = __builtin_amdgcn_readfirstlane(threadIdx.x >> 6);
    const int bf = flags[0];

    float w[64];
    #pragma unroll
    for (int k = 0; k < 64; ++k) w[k] = WT[k * 64 + lane];
    const float bs = bias[lane];

    const int wv = blockIdx.x * 4 + wib;
    const int nw = gridDim.x * 4;
    for (int n = wv; n < NNODES; n += nw) {
        float a0 = 0.f, a1 = 0.f, a2 = 0.f, a3 = 0.f;
        if (bf) {
            const uint4* xr = (const uint4*)((const unsigned short*)xv + (size_t)n * DF);
            #pragma unroll
            for (int q = 0; q < 8; ++q) {
                uint4 v = xr[q];
                float x0,x1,x2,x3,x4,x5,x6,x7;
                unpack2(v.x, x0, x1); unpack2(v.y, x2, x3);
                unpack2(v.z, x4, x5); unpack2(v.w, x6, x7);
                a0 = fmaf(x0, w[8*q+0], a0); a1 = fmaf(x1, w[8*q+1], a1);
                a2 = fmaf(x2, w[8*q+2], a2); a3 = fmaf(x3, w[8*q+3], a3);
                a0 = fmaf(x4, w[8*q+4], a0); a1 = fmaf(x5, w[8*q+5], a1);
                a2 = fmaf(x6, w[8*q+6], a2); a3 = fmaf(x7, w[8*q+7], a3);
            }
        } else {
            const float4* xr = (const float4*)((const float*)xv + (size_t)n * DF);
            #pragma unroll
            for (int q = 0; q < 16; ++q) {
                float4 v = xr[q];
                a0 = fmaf(v.x, w[4*q+0], a0); a1 = fmaf(v.y, w[4*q+1], a1);
                a2 = fmaf(v.z, w[4*q+2], a2); a3 = fmaf(v.w, w[4*q+3], a3);
            }
        }
        float r = (a0 + a1) + (a2 + a3) + bs;
        if (of) {
            ((float*)outv)[(size_t)n * DF + lane] = r;
        } else {
            size_t gi = (size_t)(lane >> 4) * SLN + (size_t)n * SW + (lane & 15);
            ((unsigned short*)outv)[gi] = f2bf(r);
        }
    }
}

// ---------- bucket histogram (LDS pre-aggregated) ----------
__global__ __launch_bounds__(256) void bhist_k(const int* __restrict__ flags,
                                               const int* __restrict__ ei,
                                               int* __restrict__ BktCnt) {
    __shared__ int h[NBUCK];
    const int i64 = flags[1];
    for (int i = threadIdx.x; i < NBUCK; i += 256) h[i] = 0;
    __syncthreads();
    int stride = gridDim.x * 256;
    for (int e = blockIdx.x * 256 + threadIdx.x; e < NEDGES; e += stride) {
        int tgt = i64 ? ei[4*e + 2] : ei[2*e + 1];
        if ((unsigned)tgt < NNODES) atomicAdd(&h[tgt / BKT], 1);
    }
    __syncthreads();
    for (int b = threadIdx.x; b < NBUCK; b += 256)
        if (h[b]) atomicAdd(BktCnt + b, h[b]);
}

// ---------- scan of 1000 bucket counts ----------
__global__ __launch_bounds__(1024) void bscan_k(const int* __restrict__ BktCnt,
                                                int* __restrict__ BktOff,
                                                int* __restrict__ BktCur) {
    __shared__ int lds[1024];
    int t = threadIdx.x;
    int c = (t < NBUCK) ? BktCnt[t] : 0;
    lds[t] = c;
    __syncthreads();
    for (int off = 1; off < 1024; off <<= 1) {
        int add = (t >= off) ? lds[t - off] : 0;
        __syncthreads();
        lds[t] += add;
        __syncthreads();
    }
    if (t < NBUCK) {
        int ex = lds[t] - c;
        BktOff[t] = ex;
        BktCur[t] = ex;
    }
    if (t == NBUCK - 1) BktOff[NBUCK] = lds[t];
}

// ---------- bucket fill: two-pass binning, packed (tl<<24 | src) ----------
__global__ __launch_bounds__(256) void bfill_k(const int* __restrict__ flags,
                                               const int* __restrict__ ei,
                                               int* __restrict__ BktCur,
                                               int* __restrict__ BktE) {
    __shared__ int h[NBUCK], h2[NBUCK], basee[NBUCK];
    const int i64 = flags[1];
    for (int i = threadIdx.x; i < NBUCK; i += 256) { h[i] = 0; h2[i] = 0; }
    __syncthreads();
    const int stride = gridDim.x * 256;
    for (int e = blockIdx.x * 256 + threadIdx.x; e < NEDGES; e += stride) {
        int tgt = i64 ? ei[4*e + 2] : ei[2*e + 1];
        if ((unsigned)tgt < NNODES) atomicAdd(&h[tgt / BKT], 1);
    }
    __syncthreads();
    for (int b = threadIdx.x; b < NBUCK; b += 256)
        if (h[b]) basee[b] = atomicAdd(BktCur + b, h[b]);
    __syncthreads();
    for (int e = blockIdx.x * 256 + threadIdx.x; e < NEDGES; e += stride) {
        int src, tgt;
        if (i64) { src = ei[4*e]; tgt = ei[4*e + 2]; }
        else     { src = ei[2*e]; tgt = ei[2*e + 1]; }
        if ((unsigned)tgt >= NNODES) continue;
        int b = tgt / BKT;
        int tl = tgt - b * BKT;
        int r = atomicAdd(&h2[b], 1);
        BktE[basee[b] + r] = (tl << 24) | (src & 0xFFFFFF);
    }
}

// ---------- per-bucket counting sort by target -> CsrSrc + Row ----------
__global__ __launch_bounds__(256) void tsort_k(const int* __restrict__ BktOff,
                                               const int* __restrict__ BktE,
                                               int* __restrict__ CsrSrc,
                                               int* __restrict__ Row) {
    __shared__ int oc[128], excl[128], cur[128];
    const int tid = threadIdx.x;
    const int b = blockIdx.x;
    const int s = BktOff[b], e = BktOff[b + 1];
    const int n = e - s;
    if (tid < 128) { oc[tid] = 0; }
    __syncthreads();
    for (int i = tid; i < n; i += 256)
        atomicAdd(&oc[((unsigned)BktE[s + i]) >> 24], 1);
    __syncthreads();
    if (tid < 128) excl[tid] = (tid > 0) ? oc[tid - 1] : 0;
    __syncthreads();
    for (int off = 1; off < 128; off <<= 1) {
        int add = (tid >= off && tid < 128) ? excl[tid - off] : 0;
        __syncthreads();
        if (tid < 128) excl[tid] += add;
        __syncthreads();
    }
    if (tid < BKT) {
        Row[b * BKT + tid] = s + excl[tid];
        cur[tid] = excl[tid];
    }
    if (b == 0 && tid == 0) Row[NNODES] = NEDGES;
    __syncthreads();
    for (int i = tid; i < n; i += 256) {
        int v = BktE[s + i];
        int tl = ((unsigned)v) >> 24;
        int p = atomicAdd(&cur[tl], 1);
        CsrSrc[s + p] = v & 0xFFFFFF;
    }
}

// ---------- chunk -> first-target table (hoists agg's binary searches) ----------
// ChunkT[c] = first t with Row[t] >= c*CHUNK ; ChunkT[NCHUNK] = NNODES.
__global__ __launch_bounds__(256) void cstart_k(const int* __restrict__ Row,
                                                int* __restrict__ ChunkT) {
    int c = blockIdx.x * 256 + threadIdx.x;
    if (c > NCHUNK) return;
    if (c == NCHUNK) { ChunkT[NCHUNK] = NNODES; return; }
    int target = c * CHUNK;
    int lo = 0, hi = NNODES + 1;
    while (lo < hi) { int mid = (lo + hi) >> 1; if (Row[mid] >= target) hi = mid; else lo = mid + 1; }
    ChunkT[c] = lo;
}

// ---------- aggregation: dim-sliced, 4 independent gather chains ----------
// Ps/Pt/Msg sliced [NSL][N][SW]; slice = blockIdx&3 (XCD-paired, proven locality:
// R8 FETCH 91.5->54.9 MB). R8's regression fixed: (a) binary searches hoisted to
// cstart_k, (b) 16-edge body with 4 independent load->gather chains + 4 accs
// (R8 had 2 chains, VGPR=12, no pipelining).
__global__ __launch_bounds__(256) void agg_k(const unsigned short* __restrict__ Ps,
                                             const unsigned short* __restrict__ Pt,
                                             const int* __restrict__ Row,
                                             const int* __restrict__ CsrSrc,
                                             const int* __restrict__ ChunkT,
                                             unsigned short* __restrict__ Msg) {
    const int lane = threadIdx.x & 63;
    const int wib = __builtin_amdgcn_readfirstlane(threadIdx.x >> 6);
    const int sl = blockIdx.x & 3;
    const int c = (blockIdx.x >> 2) * 4 + wib;
    if (c >= NCHUNK) return;
    const int d  = lane & 15;
    const int eg = lane >> 4;     // edge slot 0..3

    const unsigned short* Ps_s = Ps + (size_t)sl * SLN;
    const unsigned short* Pt_s = Pt + (size_t)sl * SLN;
    unsigned short*       Ms_s = Msg + (size_t)sl * SLN;

    const int t_lo = ChunkT[c];
    const int t_hi = ChunkT[c + 1];

    for (int t = t_lo; t < t_hi; ++t) {
        const int segS = Row[t], segE = Row[t + 1];
        const int deg = segE - segS;
        float ptv = bf2f(Pt_s[(size_t)t * SW + d]);
        float m0 = 0.f, m1 = 0.f, m2 = 0.f, m3 = 0.f;
        int i = segS;
        for (; i + 16 <= segE; i += 16) {
            int sA = CsrSrc[i      + eg];
            int sB = CsrSrc[i + 4  + eg];
            int sC = CsrSrc[i + 8  + eg];
            int sD = CsrSrc[i + 12 + eg];
            if ((unsigned)sA >= NNODES) sA = 0;
            if ((unsigned)sB >= NNODES) sB = 0;
            if ((unsigned)sC >= NNODES) sC = 0;
            if ((unsigned)sD >= NNODES) sD = 0;
            float pA = bf2f(Ps_s[(size_t)sA * SW + d]);
            float pB = bf2f(Ps_s[(size_t)sB * SW + d]);
            float pC = bf2f(Ps_s[(size_t)sC * SW + d]);
            float pD = bf2f(Ps_s[(size_t)sD * SW + d]);
            m0 += fmaxf(pA + ptv, 0.f);
            m1 += fmaxf(pB + ptv, 0.f);
            m2 += fmaxf(pC + ptv, 0.f);
            m3 += fmaxf(pD + ptv, 0.f);
        }
        float macc = (m0 + m1) + (m2 + m3);
        for (; i < segE; i += 4) {
            int idx = i + eg;
            int ok = idx < segE;
            int s = CsrSrc[ok ? idx : segS];
            if ((unsigned)s >= NNODES) s = 0;
            float p = bf2f(Ps_s[(size_t)s * SW + d]);
            macc += ok ? fmaxf(p + ptv, 0.f) : 0.f;
        }
        // reduce across the 4 edge-slot groups (lanes differing in bits 4,5)
        macc += __shfl_xor(macc, 16, 64);
        macc += __shfl_xor(macc, 32, 64);
        float mval = (deg > 0) ? (macc / (float)deg) : 0.f;
        if (lane < 16) Ms_s[(size_t)t * SW + d] = f2bf(mval);
    }
}

// ---------- u2: r = relu(t1 + Msg@Wu_m^T) + x ; LayerNorm ; out ----------
// wave = node, lane = dim. Only Wu_m (64 floats) in registers. Msg is sliced.
__global__ __launch_bounds__(256, 1) void u2_k(const int* __restrict__ flags,
                                               const void* __restrict__ xv,
                                               const unsigned short* __restrict__ Msg,
                                               const float* __restrict__ t1,
                                               const float* __restrict__ WT,
                                               const float* __restrict__ prm,
                                               void* __restrict__ outv) {
    const int lane = threadIdx.x & 63;
    const int wib = __builtin_amdgcn_readfirstlane(threadIdx.x >> 6);
    const int bf = flags[0];

    float w[64];
    #pragma unroll
    for (int k = 0; k < 64; ++k) w[k] = WT[k * 64 + lane];
    const float ga = prm[128 + lane];
    const float be = prm[192 + lane];

    const unsigned short* x16 = (const unsigned short*)xv;
    const float* xf = (const float*)xv;

    const int wv = blockIdx.x * 4 + wib;
    const int nw = gridDim.x * 4;
    for (int n = wv; n < NNODES; n += nw) {
        float b0 = 0.f, b1 = 0.f, b2 = 0.f, b3 = 0.f;
        #pragma unroll
        for (int s4 = 0; s4 < NSL; ++s4) {
            const uint4* mw = (const uint4*)(Msg + (size_t)s4 * SLN + (size_t)n * SW);
            #pragma unroll
            for (int q = 0; q < 2; ++q) {
                uint4 v = mw[q];
                const int kb = s4 * 16 + q * 8;
                float m0,m1,m2,m3,m4,m5,m6,m7;
                unpack2(v.x, m0, m1); unpack2(v.y, m2, m3);
                unpack2(v.z, m4, m5); unpack2(v.w, m6, m7);
                b0 = fmaf(m0, w[kb+0], b0); b1 = fmaf(m1, w[kb+1], b1);
                b2 = fmaf(m2, w[kb+2], b2); b3 = fmaf(m3, w[kb+3], b3);
                b0 = fmaf(m4, w[kb+4], b0); b1 = fmaf(m5, w[kb+5], b1);
                b2 = fmaf(m6, w[kb+6], b2); b3 = fmaf(m7, w[kb+7], b3);
            }
        }
        size_t gi = (size_t)n * DF + lane;
        float t  = t1[gi];
        float xl = bf ? bf2f(x16[gi]) : xf[gi];
        float u = fmaxf((b0 + b1) + (b2 + b3) + t, 0.f);
        float r = u + xl;

        float s = r, s2 = r * r;
        #pragma unroll
        for (int m = 1; m < 64; m <<= 1) {
            s  += __shfl_xor(s, m, 64);
            s2 += __shfl_xor(s2, m, 64);
        }
        float mu  = s * (1.0f / 64.0f);
        float var = fmaxf(s2 * (1.0f / 64.0f) - mu * mu, 0.f);
        float o = (r - mu) * rsqrtf(var + 1e-5f) * ga + be;

        if (bf) ((__hip_bfloat16*)outv)[gi] = __float2bfloat16(o);
        else    ((float*)outv)[gi] = o;
    }
}

extern "C" void kernel_launch(void* const* d_in, const int* in_sizes, int n_in,
                              void* d_out, int out_size, void* d_ws, size_t ws_size,
                              hipStream_t stream) {
    const void* x  = d_in[0];
    const int*  ei = (const int*)d_in[1];
    const void* Wm = d_in[2];
    const void* bm = d_in[3];
    const void* Wu = d_in[4];
    const void* bu = d_in[5];
    const void* ga = d_in[6];
    const void* be = d_in[7];

    char* ws = (char*)d_ws;
    size_t off = 0;
    unsigned short* Ps  = (unsigned short*)(ws + off); off += (size_t)ND * 2;   // 12.8 MB (sliced)
    unsigned short* Pt  = (unsigned short*)(ws + off); off += (size_t)ND * 2;   // 12.8 MB (sliced)
    unsigned short* Msg = (unsigned short*)(ws + off); off += (size_t)ND * 2;   // 12.8 MB (sliced)
    int*   BktE   = (int*)(ws + off); off += (size_t)NEDGES * 4;                // 6.4 MB
    int*   CsrSrc = (int*)(ws + off); off += (size_t)NEDGES * 4;                // 6.4 MB
    int*   Row    = (int*)(ws + off); off += (size_t)(NNODES + 1) * 4;
    int*   BktCnt = (int*)(ws + off); off += NBUCK * 4;                         // memset 0
    int*   BktOff = (int*)(ws + off); off += (NBUCK + 1) * 4;
    int*   BktCur = (int*)(ws + off); off += NBUCK * 4;
    int*   flg    = (int*)(ws + off); off += 16;
    float* WfMT   = (float*)(ws + off); off += 8192 * 4;
    float* WfUT   = (float*)(ws + off); off += 8192 * 4;
    float* prm    = (float*)(ws + off); off += 320 * 4;

    // t1 (fp32, 25.6 MB) reuses Ps+Pt region — valid because mm_k(t1) runs AFTER agg_k.
    float* t1 = (float*)Ps;
    // ChunkT (12501 ints) aliases BktE — dead after tsort_k.
    int* ChunkT = BktE;

    (void)hipMemsetAsync(BktCnt, 0, NBUCK * 4, stream);

    detect_k<<<1, 256, 0, stream>>>((const unsigned short*)x, (const unsigned int*)ei, flg);
    // 66 blocks: covers 16384 weight elems + 320 prm elems
    wconv_k<<<66, 256, 0, stream>>>(flg, Wm, Wu, bm, bu, ga, be, WfMT, WfUT, prm);

    // Ps = x@Wm_s^T (no bias -> zero slot prm+256) ; Pt = x@Wm_t^T + b_msg  (sliced bf16)
    mm_k<<<1024, 256, 0, stream>>>(flg, x, WfMT,        prm + 256, Ps, 0);
    mm_k<<<1024, 256, 0, stream>>>(flg, x, WfMT + 4096, prm,       Pt, 0);

    bhist_k<<<256, 256, 0, stream>>>(flg, ei, BktCnt);
    bscan_k<<<1, 1024, 0, stream>>>(BktCnt, BktOff, BktCur);
    bfill_k<<<128, 256, 0, stream>>>(flg, ei, BktCur, BktE);
    tsort_k<<<NBUCK, 256, 0, stream>>>(BktOff, BktE, CsrSrc, Row);

    // chunk->target table (one search per chunk; BktE is dead, reuse as ChunkT)
    cstart_k<<<(NCHUNK + 256) / 256, 256, 0, stream>>>(Row, ChunkT);

    // 12500 blocks: slice = bid&3 (XCD-paired), 4 chunks per block (one per wave)
    agg_k<<<NCHUNK, 256, 0, stream>>>(Ps, Pt, Row, CsrSrc, ChunkT, Msg);

    // t1 = x@Wu_x^T + b_upd (fp32 row-major), overwrites Ps/Pt (now dead)
    mm_k<<<1024, 256, 0, stream>>>(flg, x, WfUT, prm + 64, t1, 1);

    u2_k<<<1024, 256, 0, stream>>>(flg, x, Msg, t1, WfUT + 4096, prm, d_out);
}

// Round 10
// 329.894 us; speedup vs baseline: 1.2501x; 1.2266x over previous
//
#include <hip/hip_runtime.h>
#include <hip/hip_bf16.h>
#include <stdint.h>

#define NNODES 100000
#define DF 64
#define NEDGES 1600000
#define ND (NNODES * DF)     // 6,400,000
#define BKT 100              // targets per bucket
#define NBUCK 1000           // BKT*NBUCK == NNODES
#define CHUNK 128            // edges per wave in agg_k
#define NCHUNK (NEDGES / CHUNK)   // 12500
#define NPW 25               // nodes per wave in mm/u2 (4096 waves * 25 >= NNODES)

// ---------- helpers ----------
static __device__ __forceinline__ float bf2f(unsigned short u) {
    union { uint32_t i; float f; } c; c.i = ((uint32_t)u) << 16; return c.f;
}
static __device__ __forceinline__ unsigned short f2bf(float f) {
    union { __hip_bfloat16 b; unsigned short u; } c; c.b = __float2bfloat16(f); return c.u;
}
static __device__ __forceinline__ void unpack2(uint32_t u, float& lo, float& hi) {
    union { uint32_t i; float f; } a, b;
    a.i = u << 16; b.i = u & 0xFFFF0000u;
    lo = a.f; hi = b.f;
}

// ---------- dtype detector: flags[0]=bf16?, flags[1]=int64? ----------
__global__ void detect_k(const unsigned short* __restrict__ x,
                         const unsigned int* __restrict__ ei,
                         int* __restrict__ flags) {
    __shared__ int cnt_sane, cnt_odd_nz;
    if (threadIdx.x == 0) { cnt_sane = 0; cnt_odd_nz = 0; }
    __syncthreads();
    unsigned short s = x[threadIdx.x * 2];
    unsigned short m = s & 0x7FFF;
    if (m < 0x0080 || (m >= 0x3000 && m <= 0x4200)) atomicAdd(&cnt_sane, 1);
    if (threadIdx.x < 64) {
        if (ei[threadIdx.x * 2 + 1] != 0u) atomicAdd(&cnt_odd_nz, 1);
    }
    __syncthreads();
    if (threadIdx.x == 0) {
        flags[0] = (cnt_sane >= 192) ? 1 : 0;
        flags[1] = (cnt_odd_nz == 0) ? 1 : 0;
    }
}

// ---------- weight canonicalization -> fp32 TRANSPOSED ----------
// WfMT layout: [half][k][j] : half 0 = Wm_s, half 1 = Wm_t ; element = W[j][k]
// WfUT layout: half 0 = Wu_x, half 1 = Wu_m
// prm: [0:64)=b_msg [64:128)=b_upd [128:192)=gamma [192:256)=beta [256:320)=0
__global__ void wconv_k(const int* __restrict__ flags,
                        const void* __restrict__ Wm, const void* __restrict__ Wu,
                        const void* __restrict__ bm, const void* __restrict__ bu,
                        const void* __restrict__ ga, const void* __restrict__ be,
                        float* __restrict__ WfMT, float* __restrict__ WfUT,
                        float* __restrict__ prm) {
    const int bf = flags[0];
    int i = blockIdx.x * 256 + threadIdx.x;
    if (i < 16384) {
        const void* src = (i < 8192) ? Wm : Wu;
        float* dst = (i < 8192) ? WfMT : WfUT;
        int ii = i & 8191, j = ii >> 6, k = ii & 63;
        int si = (j & 63) * 128 + ((j >> 6) ? 64 : 0) + k;
        float v = bf ? bf2f(((const unsigned short*)src)[si]) : ((const float*)src)[si];
        dst[(j >> 6) * 4096 + k * 64 + (j & 63)] = v;
    } else if (i < 16384 + 320) {
        int t = i - 16384, which = t >> 6, k = t & 63;
        if (which == 4) { prm[t] = 0.f; }
        else {
            const void* p = (which == 0) ? bm : (which == 1) ? bu : (which == 2) ? ga : be;
            prm[t] = bf ? bf2f(((const unsigned short*)p)[k]) : ((const float*)p)[k];
        }
    }
}

// ---------- generic row-matmul: out[n][j] = sum_k in[n][k] * WT[k][j] + bias[j] ----------
// wave = contiguous run of NPW nodes (sequential row streaming), lane = output dim j.
// Weights in 64 registers per lane. of=1 -> fp32 out, of=0 -> bf16 out (row-major).
__global__ __launch_bounds__(256, 1) void mm_k(const int* __restrict__ flags,
                                               const void* __restrict__ xv,
                                               const float* __restrict__ WT,
                                               const float* __restrict__ bias,
                                               void* __restrict__ outv,
                                               int of) {
    const int lane = threadIdx.x & 63;
    const int wib = __builtin_amdgcn_readfirstlane(threadIdx.x >> 6);
    const int bf = flags[0];

    float w[64];
    #pragma unroll
    for (int k = 0; k < 64; ++k) w[k] = WT[k * 64 + lane];
    const float bs = bias[lane];

    const int wv = blockIdx.x * 4 + wib;
    const int n0 = wv * NPW;
    if (n0 >= NNODES) return;
    const int n1 = (n0 + NPW < NNODES) ? n0 + NPW : NNODES;
    for (int n = n0; n < n1; ++n) {
        float a0 = 0.f, a1 = 0.f, a2 = 0.f, a3 = 0.f;
        if (bf) {
            const uint4* xr = (const uint4*)((const unsigned short*)xv + (size_t)n * DF);
            #pragma unroll
            for (int q = 0; q < 8; ++q) {
                uint4 v = xr[q];
                float x0,x1,x2,x3,x4,x5,x6,x7;
                unpack2(v.x, x0, x1); unpack2(v.y, x2, x3);
                unpack2(v.z, x4, x5); unpack2(v.w, x6, x7);
                a0 = fmaf(x0, w[8*q+0], a0); a1 = fmaf(x1, w[8*q+1], a1);
                a2 = fmaf(x2, w[8*q+2], a2); a3 = fmaf(x3, w[8*q+3], a3);
                a0 = fmaf(x4, w[8*q+4], a0); a1 = fmaf(x5, w[8*q+5], a1);
                a2 = fmaf(x6, w[8*q+6], a2); a3 = fmaf(x7, w[8*q+7], a3);
            }
        } else {
            const float4* xr = (const float4*)((const float*)xv + (size_t)n * DF);
            #pragma unroll
            for (int q = 0; q < 16; ++q) {
                float4 v = xr[q];
                a0 = fmaf(v.x, w[4*q+0], a0); a1 = fmaf(v.y, w[4*q+1], a1);
                a2 = fmaf(v.z, w[4*q+2], a2); a3 = fmaf(v.w, w[4*q+3], a3);
            }
        }
        float r = (a0 + a1) + (a2 + a3) + bs;
        size_t gi = (size_t)n * DF + lane;
        if (of) ((float*)outv)[gi] = r;
        else    ((unsigned short*)outv)[gi] = f2bf(r);
    }
}

// ---------- bucket histogram (LDS pre-aggregated) ----------
__global__ __launch_bounds__(256) void bhist_k(const int* __restrict__ flags,
                                               const int* __restrict__ ei,
                                               int* __restrict__ BktCnt) {
    __shared__ int h[NBUCK];
    const int i64 = flags[1];
    for (int i = threadIdx.x; i < NBUCK; i += 256) h[i] = 0;
    __syncthreads();
    int stride = gridDim.x * 256;
    for (int e = blockIdx.x * 256 + threadIdx.x; e < NEDGES; e += stride) {
        int tgt = i64 ? ei[4*e + 2] : ei[2*e + 1];
        if ((unsigned)tgt < NNODES) atomicAdd(&h[tgt / BKT], 1);
    }
    __syncthreads();
    for (int b = threadIdx.x; b < NBUCK; b += 256)
        if (h[b]) atomicAdd(BktCnt + b, h[b]);
}

// ---------- scan of 1000 bucket counts ----------
__global__ __launch_bounds__(1024) void bscan_k(const int* __restrict__ BktCnt,
                                                int* __restrict__ BktOff,
                                                int* __restrict__ BktCur) {
    __shared__ int lds[1024];
    int t = threadIdx.x;
    int c = (t < NBUCK) ? BktCnt[t] : 0;
    lds[t] = c;
    __syncthreads();
    for (int off = 1; off < 1024; off <<= 1) {
        int add = (t >= off) ? lds[t - off] : 0;
        __syncthreads();
        lds[t] += add;
        __syncthreads();
    }
    if (t < NBUCK) {
        int ex = lds[t] - c;
        BktOff[t] = ex;
        BktCur[t] = ex;
    }
    if (t == NBUCK - 1) BktOff[NBUCK] = lds[t];
}

// ---------- bucket fill: two-pass binning, packed (tl<<24 | src) ----------
__global__ __launch_bounds__(256) void bfill_k(const int* __restrict__ flags,
                                               const int* __restrict__ ei,
                                               int* __restrict__ BktCur,
                                               int* __restrict__ BktE) {
    __shared__ int h[NBUCK], h2[NBUCK], basee[NBUCK];
    const int i64 = flags[1];
    for (int i = threadIdx.x; i < NBUCK; i += 256) { h[i] = 0; h2[i] = 0; }
    __syncthreads();
    const int stride = gridDim.x * 256;
    for (int e = blockIdx.x * 256 + threadIdx.x; e < NEDGES; e += stride) {
        int tgt = i64 ? ei[4*e + 2] : ei[2*e + 1];
        if ((unsigned)tgt < NNODES) atomicAdd(&h[tgt / BKT], 1);
    }
    __syncthreads();
    for (int b = threadIdx.x; b < NBUCK; b += 256)
        if (h[b]) basee[b] = atomicAdd(BktCur + b, h[b]);
    __syncthreads();
    for (int e = blockIdx.x * 256 + threadIdx.x; e < NEDGES; e += stride) {
        int src, tgt;
        if (i64) { src = ei[4*e]; tgt = ei[4*e + 2]; }
        else     { src = ei[2*e]; tgt = ei[2*e + 1]; }
        if ((unsigned)tgt >= NNODES) continue;
        int b = tgt / BKT;
        int tl = tgt - b * BKT;
        int r = atomicAdd(&h2[b], 1);
        BktE[basee[b] + r] = (tl << 24) | (src & 0xFFFFFF);
    }
}

// ---------- per-bucket counting sort by target -> CsrSrc + Row ----------
// CsrSrc entries are pre-clamped and PRE-MULTIPLIED by DF (row element offset),
// so agg_k's gather needs no clamp/shift.
__global__ __launch_bounds__(256) void tsort_k(const int* __restrict__ BktOff,
                                               const int* __restrict__ BktE,
                                               int* __restrict__ CsrSrc,
                                               int* __restrict__ Row) {
    __shared__ int oc[128], excl[128], cur[128];
    const int tid = threadIdx.x;
    const int b = blockIdx.x;
    const int s = BktOff[b], e = BktOff[b + 1];
    const int n = e - s;
    if (tid < 128) { oc[tid] = 0; }
    __syncthreads();
    for (int i = tid; i < n; i += 256)
        atomicAdd(&oc[((unsigned)BktE[s + i]) >> 24], 1);
    __syncthreads();
    if (tid < 128) excl[tid] = (tid > 0) ? oc[tid - 1] : 0;
    __syncthreads();
    for (int off = 1; off < 128; off <<= 1) {
        int add = (tid >= off && tid < 128) ? excl[tid - off] : 0;
        __syncthreads();
        if (tid < 128) excl[tid] += add;
        __syncthreads();
    }
    if (tid < BKT) {
        Row[b * BKT + tid] = s + excl[tid];
        cur[tid] = excl[tid];
    }
    if (b == 0 && tid == 0) Row[NNODES] = NEDGES;
    __syncthreads();
    for (int i = tid; i < n; i += 256) {
        int v = BktE[s + i];
        int tl = ((unsigned)v) >> 24;
        int p = atomicAdd(&cur[tl], 1);
        int sv = v & 0xFFFFFF;
        if (sv >= NNODES) sv = 0;
        CsrSrc[s + p] = sv << 6;   // * DF
    }
}

// ---------- chunk -> first-target table (hoists agg's binary searches) ----------
__global__ __launch_bounds__(256) void cstart_k(const int* __restrict__ Row,
                                                int* __restrict__ ChunkT) {
    int c = blockIdx.x * 256 + threadIdx.x;
    if (c > NCHUNK) return;
    if (c == NCHUNK) { ChunkT[NCHUNK] = NNODES; return; }
    int target = c * CHUNK;
    int lo = 0, hi = NNODES + 1;
    while (lo < hi) { int mid = (lo + hi) >> 1; if (Row[mid] >= target) hi = mid; else lo = mid + 1; }
    ChunkT[c] = lo;
}

// ---------- aggregation: lane = dim (R4 form), masked-16 gather pipeline ----------
// R9 post-mortem: dim-slicing replicated per-edge/per-target issue 4x (VALU-busy
// 14.5us -> 58us) for a 6us HBM saving — net loss. Revert to full-row gathers;
// keep ChunkT hoist; masked-16 body keeps 16 gathers in flight even for short
// segments (R4's serial 1-at-a-time tail was a latency chain).
__global__ __launch_bounds__(256) void agg_k(const unsigned short* __restrict__ Ps,
                                             const unsigned short* __restrict__ Pt,
                                             const int* __restrict__ Row,
                                             const int* __restrict__ CsrSrc,
                                             const int* __restrict__ ChunkT,
                                             unsigned short* __restrict__ Msg) {
    const int lane = threadIdx.x & 63;
    const int wib = __builtin_amdgcn_readfirstlane(threadIdx.x >> 6);
    const int w = blockIdx.x * 4 + wib;
    if (w >= NCHUNK) return;

    const int t_lo = ChunkT[w];
    const int t_hi = ChunkT[w + 1];
    if (t_lo >= t_hi) return;

    int segS = Row[t_lo];
    for (int t = t_lo; t < t_hi; ++t) {
        const int segE = Row[t + 1];
        const int deg = segE - segS;
        float ptv = bf2f(Pt[(size_t)t * DF + lane]);
        float pa0 = 0.f, pa1 = 0.f, pa2 = 0.f, pa3 = 0.f;
        for (int i = segS; i < segE; i += 16) {
            #pragma unroll
            for (int j = 0; j < 16; ++j) {
                const int idx = i + j;
                const int ok = idx < segE;
                const int sv = CsrSrc[ok ? idx : segS];   // pre-clamped, pre-*DF
                float p = bf2f(Ps[(size_t)(unsigned)sv + lane]);
                float v = ok ? fmaxf(p + ptv, 0.f) : 0.f;
                if ((j & 3) == 0)      pa0 += v;
                else if ((j & 3) == 1) pa1 += v;
                else if ((j & 3) == 2) pa2 += v;
                else                   pa3 += v;
            }
        }
        float macc = (pa0 + pa1) + (pa2 + pa3);
        float mval = (deg > 0) ? (macc / (float)deg) : 0.f;
        Msg[(size_t)t * DF + lane] = f2bf(mval);
        segS = segE;
    }
}

// ---------- u2: r = relu(t1 + Msg@Wu_m^T) + x ; LayerNorm ; out ----------
// wave = contiguous run of NPW nodes, lane = dim. Wu_m (64 floats) in registers.
__global__ __launch_bounds__(256, 1) void u2_k(const int* __restrict__ flags,
                                               const void* __restrict__ xv,
                                               const unsigned short* __restrict__ Msg,
                                               const float* __restrict__ t1,
                                               const float* __restrict__ WT,
                                               const float* __restrict__ prm,
                                               void* __restrict__ outv) {
    const int lane = threadIdx.x & 63;
    const int wib = __builtin_amdgcn_readfirstlane(threadIdx.x >> 6);
    const int bf = flags[0];

    float w[64];
    #pragma unroll
    for (int k = 0; k < 64; ++k) w[k] = WT[k * 64 + lane];
    const float ga = prm[128 + lane];
    const float be = prm[192 + lane];

    const unsigned short* x16 = (const unsigned short*)xv;
    const float* xf = (const float*)xv;

    const int wv = blockIdx.x * 4 + wib;
    const int n0 = wv * NPW;
    if (n0 >= NNODES) return;
    const int n1 = (n0 + NPW < NNODES) ? n0 + NPW : NNODES;
    for (int n = n0; n < n1; ++n) {
        float b0 = 0.f, b1 = 0.f, b2 = 0.f, b3 = 0.f;
        const uint4* mw = (const uint4*)(Msg + (size_t)n * DF);
        #pragma unroll
        for (int q = 0; q < 8; ++q) {
            uint4 v = mw[q];
            float m0,m1,m2,m3,m4,m5,m6,m7;
            unpack2(v.x, m0, m1); unpack2(v.y, m2, m3);
            unpack2(v.z, m4, m5); unpack2(v.w, m6, m7);
            b0 = fmaf(m0, w[8*q+0], b0); b1 = fmaf(m1, w[8*q+1], b1);
            b2 = fmaf(m2, w[8*q+2], b2); b3 = fmaf(m3, w[8*q+3], b3);
            b0 = fmaf(m4, w[8*q+4], b0); b1 = fmaf(m5, w[8*q+5], b1);
            b2 = fmaf(m6, w[8*q+6], b2); b3 = fmaf(m7, w[8*q+7], b3);
        }
        size_t gi = (size_t)n * DF + lane;
        float t  = t1[gi];
        float xl = bf ? bf2f(x16[gi]) : xf[gi];
        float u = fmaxf((b0 + b1) + (b2 + b3) + t, 0.f);
        float r = u + xl;

        float s = r, s2 = r * r;
        #pragma unroll
        for (int m = 1; m < 64; m <<= 1) {
            s  += __shfl_xor(s, m, 64);
            s2 += __shfl_xor(s2, m, 64);
        }
        float mu  = s * (1.0f / 64.0f);
        float var = fmaxf(s2 * (1.0f / 64.0f) - mu * mu, 0.f);
        float o = (r - mu) * rsqrtf(var + 1e-5f) * ga + be;

        if (bf) ((__hip_bfloat16*)outv)[gi] = __float2bfloat16(o);
        else    ((float*)outv)[gi] = o;
    }
}

extern "C" void kernel_launch(void* const* d_in, const int* in_sizes, int n_in,
                              void* d_out, int out_size, void* d_ws, size_t ws_size,
                              hipStream_t stream) {
    const void* x  = d_in[0];
    const int*  ei = (const int*)d_in[1];
    const void* Wm = d_in[2];
    const void* bm = d_in[3];
    const void* Wu = d_in[4];
    const void* bu = d_in[5];
    const void* ga = d_in[6];
    const void* be = d_in[7];

    char* ws = (char*)d_ws;
    size_t off = 0;
    unsigned short* Ps  = (unsigned short*)(ws + off); off += (size_t)ND * 2;   // 12.8 MB
    unsigned short* Pt  = (unsigned short*)(ws + off); off += (size_t)ND * 2;   // 12.8 MB
    unsigned short* Msg = (unsigned short*)(ws + off); off += (size_t)ND * 2;   // 12.8 MB
    int*   BktE   = (int*)(ws + off); off += (size_t)NEDGES * 4;                // 6.4 MB
    int*   CsrSrc = (int*)(ws + off); off += (size_t)NEDGES * 4;                // 6.4 MB
    int*   Row    = (int*)(ws + off); off += (size_t)(NNODES + 1) * 4;
    int*   BktCnt = (int*)(ws + off); off += NBUCK * 4;                         // memset 0
    int*   BktOff = (int*)(ws + off); off += (NBUCK + 1) * 4;
    int*   BktCur = (int*)(ws + off); off += NBUCK * 4;
    int*   flg    = (int*)(ws + off); off += 16;
    float* WfMT   = (float*)(ws + off); off += 8192 * 4;
    float* WfUT   = (float*)(ws + off); off += 8192 * 4;
    float* prm    = (float*)(ws + off); off += 320 * 4;

    // t1 (fp32, 25.6 MB) reuses Ps+Pt region — valid because mm_k(t1) runs AFTER agg_k.
    float* t1 = (float*)Ps;
    // ChunkT (12501 ints) aliases BktE — dead after tsort_k.
    int* ChunkT = BktE;

    (void)hipMemsetAsync(BktCnt, 0, NBUCK * 4, stream);

    detect_k<<<1, 256, 0, stream>>>((const unsigned short*)x, (const unsigned int*)ei, flg);
    // 66 blocks: covers 16384 weight elems + 320 prm elems
    wconv_k<<<66, 256, 0, stream>>>(flg, Wm, Wu, bm, bu, ga, be, WfMT, WfUT, prm);

    // Ps = x@Wm_s^T (no bias -> zero slot prm+256) ; Pt = x@Wm_t^T + b_msg
    mm_k<<<1024, 256, 0, stream>>>(flg, x, WfMT,        prm + 256, Ps, 0);
    mm_k<<<1024, 256, 0, stream>>>(flg, x, WfMT + 4096, prm,       Pt, 0);

    bhist_k<<<256, 256, 0, stream>>>(flg, ei, BktCnt);
    bscan_k<<<1, 1024, 0, stream>>>(BktCnt, BktOff, BktCur);
    bfill_k<<<128, 256, 0, stream>>>(flg, ei, BktCur, BktE);
    tsort_k<<<NBUCK, 256, 0, stream>>>(BktOff, BktE, CsrSrc, Row);

    // chunk->target table (one search per chunk; BktE is dead, reuse as ChunkT)
    cstart_k<<<(NCHUNK + 256) / 256, 256, 0, stream>>>(Row, ChunkT);

    agg_k<<<(NCHUNK + 3) / 4, 256, 0, stream>>>(Ps, Pt, Row, CsrSrc, ChunkT, Msg);

    // t1 = x@Wu_x^T + b_upd (fp32 row-major), overwrites Ps/Pt (now dead)
    mm_k<<<1024, 256, 0, stream>>>(flg, x, WfUT, prm + 64, t1, 1);

    u2_k<<<1024, 256, 0, stream>>>(flg, x, Msg, t1, WfUT + 4096, prm, d_out);
}